// Round 6
// baseline (287.821 us; speedup 1.0000x reference)
//
#include <hip/hip_runtime.h>
#include <math.h>

#define Bz 8
#define NQ 4096
#define NKV 4096
#define Cc 256
#define KNN 16
#define Hh 32
#define EPSf 1e-5f
#define SLOPEf 0.2f

typedef unsigned long long u64t;
typedef unsigned int u32t;

// ---- workspace layout (bytes) ----
#define OFF_W1AS 0u                       // 32*256 f32 (alpha1-folded w1a)
#define OFF_W1DS (OFF_W1AS + 32768u)      // 32*256 f32 (alpha1-folded (w1b-w1a))
#define OFF_W2T  (OFF_W1DS + 32768u)      // 32*256 f32 w2t[h][c] = alpha2[c]*w2[c][h]
#define OFF_C1   (OFF_W2T + 32768u)       // 32 f32: b1 - alpha1*m1
#define OFF_B2F  (OFF_C1 + 1024u)         // 256 f32: b2 - alpha2*m2
#define OFF_KVP  (OFF_B2F + 2048u)        // 8*4096 float4 kv xyz (w = |k|^2)
#define OFF_QP   (OFF_KVP + 524288u)      // 8*4096 float4 q xyz (w = |q|^2 + 1)
#define OFF_KVS  (OFF_QP + 524288u)       // 8*4096*32 f32
#define OFF_QADD (OFF_KVS + 4194304u)     // 8*4096*32 f32
#define OFF_PD   (OFF_QADD + 4194304u)    // 8*4096*NSL*16 f64 per-slice sorted keys

__device__ __forceinline__ float leaky(float x) { return fmaxf(x, SLOPEf * x); }

// f64 comparators: CAS = v_min_f64 + v_max_f64 (2 instrs); MN2 = v_min_f64 (1)
#define CASD(A, B) { double lo_ = fmin(A, B); double hi_ = fmax(A, B); (A) = lo_; (B) = hi_; }
#define MND(A, B)  { (A) = fmin(A, B); }

// Batcher odd-even mergesort, 16 elements, 63 comparators (c0..c15 ascending)
#define SORTC16 \
  CASD(c0,c1) CASD(c2,c3) CASD(c4,c5) CASD(c6,c7) CASD(c8,c9) CASD(c10,c11) CASD(c12,c13) CASD(c14,c15) \
  CASD(c0,c2) CASD(c4,c6) CASD(c8,c10) CASD(c12,c14) CASD(c1,c3) CASD(c5,c7) CASD(c9,c11) CASD(c13,c15) \
  CASD(c1,c2) CASD(c5,c6) CASD(c9,c10) CASD(c13,c14) \
  CASD(c0,c4) CASD(c8,c12) CASD(c1,c5) CASD(c9,c13) CASD(c2,c6) CASD(c10,c14) CASD(c3,c7) CASD(c11,c15) \
  CASD(c2,c4) CASD(c10,c12) CASD(c3,c5) CASD(c11,c13) \
  CASD(c1,c2) CASD(c3,c4) CASD(c5,c6) CASD(c9,c10) CASD(c11,c12) CASD(c13,c14) \
  CASD(c0,c8) CASD(c1,c9) CASD(c2,c10) CASD(c3,c11) CASD(c4,c12) CASD(c5,c13) CASD(c6,c14) CASD(c7,c15) \
  CASD(c4,c8) CASD(c5,c9) CASD(c6,c10) CASD(c7,c11) \
  CASD(c2,c4) CASD(c3,c5) CASD(c6,c8) CASD(c7,c9) CASD(c10,c12) CASD(c11,c13) \
  CASD(c1,c2) CASD(c3,c4) CASD(c5,c6) CASD(c7,c8) CASD(c9,c10) CASD(c11,c12) CASD(c13,c14)

// keep-lowest-16 of sorted b (asc) U sorted c (asc): reversed pairwise min, bitonic clean
#define MERGE16 \
  MND(b0,c15) MND(b1,c14) MND(b2,c13) MND(b3,c12) MND(b4,c11) MND(b5,c10) MND(b6,c9) MND(b7,c8) \
  MND(b8,c7) MND(b9,c6) MND(b10,c5) MND(b11,c4) MND(b12,c3) MND(b13,c2) MND(b14,c1) MND(b15,c0) \
  CASD(b0,b8) CASD(b1,b9) CASD(b2,b10) CASD(b3,b11) CASD(b4,b12) CASD(b5,b13) CASD(b6,b14) CASD(b7,b15) \
  CASD(b0,b4) CASD(b1,b5) CASD(b2,b6) CASD(b3,b7) CASD(b8,b12) CASD(b9,b13) CASD(b10,b14) CASD(b11,b15) \
  CASD(b0,b2) CASD(b1,b3) CASD(b4,b6) CASD(b5,b7) CASD(b8,b10) CASD(b9,b11) CASD(b12,b14) CASD(b13,b15) \
  CASD(b0,b1) CASD(b2,b3) CASD(b4,b5) CASD(b6,b7) CASD(b8,b9) CASD(b10,b11) CASD(b12,b13) CASD(b14,b15)

// ---------------- kernel 0: fold weights + pack xyz as float4 ----------------
__global__ __launch_bounds__(256) void k_prep(
    const float* __restrict__ qxyz, const float* __restrict__ kxyz,
    const float* __restrict__ w1, const float* __restrict__ g1,
    const float* __restrict__ b1, const float* __restrict__ m1,
    const float* __restrict__ v1, const float* __restrict__ w2,
    const float* __restrict__ g2, const float* __restrict__ b2,
    const float* __restrict__ m2, const float* __restrict__ v2,
    char* __restrict__ ws) {
  int t = threadIdx.x;
  if (blockIdx.x == 0) {
    __shared__ float a1[Hh], a2c[Cc];
    if (t < Hh) a1[t] = g1[t] / sqrtf(v1[t] + EPSf);
    if (t < Cc) a2c[t] = g2[t] / sqrtf(v2[t] + EPSf);
    __syncthreads();
    float* w1as = (float*)(ws + OFF_W1AS);
    float* w1ds = (float*)(ws + OFF_W1DS);
    float* w2t  = (float*)(ws + OFF_W2T);
    float* c1   = (float*)(ws + OFF_C1);
    float* b2f  = (float*)(ws + OFF_B2F);
    for (int i = t; i < Hh * Cc; i += 256) {
      int h = i >> 8, c = i & 255;
      float wa = w1[h * 2 * Cc + c];
      float wb = w1[h * 2 * Cc + Cc + c];
      w1as[i] = a1[h] * wa;
      w1ds[i] = a1[h] * (wb - wa);
      w2t[i] = a2c[c] * w2[c * Hh + h];   // i = h*256 + c
    }
    if (t < Hh) c1[t] = b1[t] - a1[t] * m1[t];
    if (t < Cc) b2f[t] = b2[t] - a2c[t] * m2[t];
  } else {
    // pack xyz -> float4; kv.w = |k|^2, q.w = |q|^2 + 1 (positivity bias for key order)
    float4* kvp = (float4*)(ws + OFF_KVP);
    float4* qp  = (float4*)(ws + OFF_QP);
    for (int i = 0; i < 2; ++i) {
      int g = (blockIdx.x - 1) * 512 + i * 256 + t;  // 0..65535
      if (g < Bz * NKV) {
        const float* src = kxyz + (size_t)g * 3;
        float4 v; v.x = src[0]; v.y = src[1]; v.z = src[2];
        v.w = fmaf(v.x, v.x, fmaf(v.y, v.y, v.z * v.z));
        kvp[g] = v;
      } else {
        int g2i = g - Bz * NKV;
        const float* src = qxyz + (size_t)g2i * 3;
        float4 v; v.x = src[0]; v.y = src[1]; v.z = src[2];
        v.w = fmaf(v.x, v.x, fmaf(v.y, v.y, v.z * v.z)) + 1.0f;
        qp[g2i] = v;
      }
    }
  }
}

// ------------- kernel 1: kvs = (a1*w1a)·kv_feat ; qadd = (a1*w1d)·q_feat + c1 -------------
__global__ __launch_bounds__(256) void k_feat(
    const float* __restrict__ kvf, const float* __restrict__ qf,
    const char* __restrict__ ws_c, char* __restrict__ ws_o) {
  __shared__ __align__(16) float fs[64][68];
  __shared__ __align__(16) float wsh[32][68];
  int t = threadIdx.x;
  int hh = t & 15, rr = t >> 4;
  int b = blockIdx.y, m0 = blockIdx.x * 64, mode = blockIdx.z;
  const float* in = mode ? qf : kvf;
  const float* w = (const float*)(ws_c + (mode ? OFF_W1DS : OFF_W1AS));
  const float* c1 = (const float*)(ws_c + OFF_C1);
  float* out = (float*)(ws_o + (mode ? OFF_QADD : OFF_KVS));
  const float* inb = in + ((size_t)b * NKV + m0) * Cc;
  float acc[2][4] = {{0.f, 0.f, 0.f, 0.f}, {0.f, 0.f, 0.f, 0.f}};
  for (int cc = 0; cc < 4; ++cc) {
    __syncthreads();
#pragma unroll
    for (int i = 0; i < 4; ++i) {  // stage 64x64 feat tile
      int l = i * 256 + t, row = l >> 4, c4 = l & 15;
      *(float4*)&fs[row][c4 * 4] = *(const float4*)(inb + (size_t)row * Cc + cc * 64 + c4 * 4);
    }
#pragma unroll
    for (int i = 0; i < 2; ++i) {  // stage 32x64 weight tile
      int l = i * 256 + t, row = l >> 4, c4 = l & 15;
      *(float4*)&wsh[row][c4 * 4] = *(const float4*)(w + (size_t)row * Cc + cc * 64 + c4 * 4);
    }
    __syncthreads();
#pragma unroll
    for (int c4 = 0; c4 < 16; ++c4) {
      float4 w0 = *(float4*)&wsh[hh][c4 * 4];
      float4 w1v = *(float4*)&wsh[hh + 16][c4 * 4];
#pragma unroll
      for (int j = 0; j < 4; ++j) {
        float4 f = *(float4*)&fs[rr + j * 16][c4 * 4];
        acc[0][j] = fmaf(w0.x, f.x, fmaf(w0.y, f.y, fmaf(w0.z, f.z, fmaf(w0.w, f.w, acc[0][j]))));
        acc[1][j] = fmaf(w1v.x, f.x, fmaf(w1v.y, f.y, fmaf(w1v.z, f.z, fmaf(w1v.w, f.w, acc[1][j]))));
      }
    }
  }
  float add0 = mode ? c1[hh] : 0.f;
  float add1 = mode ? c1[hh + 16] : 0.f;
  float* ob = out + ((size_t)b * NKV + m0) * Hh;
#pragma unroll
  for (int j = 0; j < 4; ++j) {
    ob[(rr + j * 16) * Hh + hh] = acc[0][j] + add0;
    ob[(rr + j * 16) * Hh + hh + 16] = acc[1][j] + add1;
  }
}

// ------------- kernel 2: per-slice EXACT top-16, f64-packed (dist,idx) keys -------------
// key = fma(double(dist_f32), 2^36, idx): exact (dist>=0.5 => ulp gap >= 4096 > idx_max),
// f64 order == (fp32 dist, global idx) lexicographic == jax top_k tie semantics.
// Candidate loads are wave-uniform -> compiler emits scalar (SMEM) loads, no LDS staging.
template <int SLt>
__global__ __launch_bounds__(256) void k_sel(
    const char* __restrict__ ws_c, double* __restrict__ pd) {
  constexpr int NSLt = NKV / SLt;
  int t = threadIdx.x;
  int qt = blockIdx.x, s = blockIdx.y, b = blockIdx.z;
  const float4* kvp = (const float4*)(ws_c + OFF_KVP) + (size_t)b * NKV + s * SLt;
  const float4* qp = (const float4*)(ws_c + OFF_QP);
  int q = qt * 256 + t;
  float4 qv = qp[(size_t)b * NQ + q];
  float qx2 = -2.0f * qv.x, qy2 = -2.0f * qv.y, qz2 = -2.0f * qv.z, qw = qv.w;
  const double SCALE = 68719476736.0;  // 2^36
  int gbase = s * SLt;
  double b0 = 1e300, b1 = 1e300, b2 = 1e300, b3 = 1e300, b4 = 1e300, b5 = 1e300, b6 = 1e300, b7 = 1e300;
  double b8 = 1e300, b9 = 1e300, b10 = 1e300, b11 = 1e300, b12 = 1e300, b13 = 1e300, b14 = 1e300, b15 = 1e300;
  double id0 = (double)(gbase + 0), id1 = (double)(gbase + 1), id2 = (double)(gbase + 2), id3 = (double)(gbase + 3);
  double id4 = (double)(gbase + 4), id5 = (double)(gbase + 5), id6 = (double)(gbase + 6), id7 = (double)(gbase + 7);
  double id8 = (double)(gbase + 8), id9 = (double)(gbase + 9), id10 = (double)(gbase + 10), id11 = (double)(gbase + 11);
  double id12 = (double)(gbase + 12), id13 = (double)(gbase + 13), id14 = (double)(gbase + 14), id15 = (double)(gbase + 15);
#define MK(J) { float4 kv = kvp[o + J]; \
  float dq = fmaf(qx2, kv.x, fmaf(qy2, kv.y, fmaf(qz2, kv.z, kv.w + qw))); \
  c##J = fma((double)dq, SCALE, id##J); id##J += 16.0; }
#pragma unroll 2
  for (int blk = 0; blk < SLt / 16; ++blk) {
    int o = blk * 16;
    double c0, c1, c2, c3, c4, c5, c6, c7, c8, c9, c10, c11, c12, c13, c14, c15;
    MK(0) MK(1) MK(2) MK(3) MK(4) MK(5) MK(6) MK(7)
    MK(8) MK(9) MK(10) MK(11) MK(12) MK(13) MK(14) MK(15)
    SORTC16
    MERGE16
  }
#undef MK
  double* ob = pd + (((size_t)b * NQ + q) * NSLt + s) * KNN;
  ob[0] = b0; ob[1] = b1; ob[2] = b2; ob[3] = b3;
  ob[4] = b4; ob[5] = b5; ob[6] = b6; ob[7] = b7;
  ob[8] = b8; ob[9] = b9; ob[10] = b10; ob[11] = b11;
  ob[12] = b12; ob[13] = b13; ob[14] = b14; ob[15] = b15;
}

// ------------- kernel 3 (fused tail): LDS tournament merge -> gather+maxpool -> matvec -------------
// block = 256 threads, 32 queries. Keys stay in LDS; merge = 16 tournament rounds with
// in-wave shfl_xor mins over NSLt consecutive lanes per query. Zero register-array pressure.
template <int NSLt>
__global__ __launch_bounds__(256) void k_tail(
    const double* __restrict__ pd, const char* __restrict__ ws_c,
    float* __restrict__ out) {
  __shared__ double keys[32 * NSLt * 17];  // per (q,sl): 16 keys + sentinel
  __shared__ int sidx[32 * 17];
  __shared__ float xs[Hh * 33];            // transposed hidden: xs[h*33 + q]
  int t = threadIdx.x;
  int b = blockIdx.y, q0 = blockIdx.x * 32;
  constexpr int LG = (NSLt == 8) ? 3 : 2;

  // ---- phase 0: load per-slice sorted lists into LDS (coalesced), set sentinels ----
  if (t < 32 * NSLt) {
    int q = t >> LG, sl = t & (NSLt - 1);
    const double* L = pd + (((size_t)b * NQ + q0 + q) * NSLt + sl) * KNN;
    double* row = &keys[(q * NSLt + sl) * 17];
#pragma unroll
    for (int j = 0; j < KNN; ++j) row[j] = L[j];
    row[KNN] = 1e300;
  }
  __syncthreads();

  // ---- phase 1: tournament merge, 16 rounds (unique keys -> exact, no ties) ----
  if (t < 32 * NSLt) {
    int q = t >> LG;
    double* row = &keys[t * 17];  // == (q*NSLt+sl)*17
    int head = 0;
    int lane0 = ((t & 63) & ~(NSLt - 1)) == (t & 63) ? 1 : 0;  // sl==0
#pragma unroll
    for (int r = 0; r < KNN; ++r) {
      double k = row[head];
      double w = k;
#pragma unroll
      for (int m = 1; m < NSLt; m <<= 1) {
        double o = __shfl_xor(w, m);
        w = fmin(w, o);
      }
      if (lane0) sidx[q * 17 + r] = (int)((u64t)w & 4095u);
      head += (k == w) ? 1 : 0;
    }
  }
  __syncthreads();

  // ---- phase 2: gather kvs rows + maxpool + qadd + leaky -> xs (transposed) ----
  {
    int q = t >> 3, j = t & 7;  // 8 lanes per query, one float4 each
    const float4* kvs = (const float4*)(ws_c + OFF_KVS) + (size_t)b * NKV * 8 + j;
    float4 p = make_float4(-3.4e38f, -3.4e38f, -3.4e38f, -3.4e38f);
#pragma unroll
    for (int n = 0; n < KNN; ++n) {
      int m = sidx[q * 17 + n];
      float4 v = kvs[(size_t)m * 8];
      p.x = fmaxf(p.x, v.x); p.y = fmaxf(p.y, v.y);
      p.z = fmaxf(p.z, v.z); p.w = fmaxf(p.w, v.w);
    }
    const float4* qa = (const float4*)(ws_c + OFF_QADD) + ((size_t)b * NQ + q0 + q) * 8 + j;
    float4 a = *qa;
    int h0 = 4 * j;
    xs[(h0 + 0) * 33 + q] = leaky(p.x + a.x);
    xs[(h0 + 1) * 33 + q] = leaky(p.y + a.y);
    xs[(h0 + 2) * 33 + q] = leaky(p.z + a.z);
    xs[(h0 + 3) * 33 + q] = leaky(p.w + a.w);
  }
  __syncthreads();

  // ---- phase 3: y = leaky(w2t · x + b2f), 32 cols per thread ----
  {
    int ql = t & 31, cb = t >> 5;  // cb in [0,8): column block of 32
    const float* w2t = (const float*)(ws_c + OFF_W2T);
    const float* b2f = (const float*)(ws_c + OFF_B2F);
    float4 acc[8];
#pragma unroll
    for (int c4 = 0; c4 < 8; ++c4) acc[c4] = make_float4(0.f, 0.f, 0.f, 0.f);
#pragma unroll
    for (int h = 0; h < Hh; ++h) {
      float xh = xs[h * 33 + ql];
      const float4* wrow = (const float4*)(w2t + (size_t)h * Cc + cb * 32);
#pragma unroll
      for (int c4 = 0; c4 < 8; ++c4) {
        float4 w = wrow[c4];
        acc[c4].x = fmaf(xh, w.x, acc[c4].x);
        acc[c4].y = fmaf(xh, w.y, acc[c4].y);
        acc[c4].z = fmaf(xh, w.z, acc[c4].z);
        acc[c4].w = fmaf(xh, w.w, acc[c4].w);
      }
    }
    float* o = out + ((size_t)b * NQ + q0 + ql) * Cc + cb * 32;
    const float4* bb = (const float4*)(b2f + cb * 32);
#pragma unroll
    for (int c4 = 0; c4 < 8; ++c4) {
      float4 bv = bb[c4];
      float4 r;
      r.x = leaky(acc[c4].x + bv.x); r.y = leaky(acc[c4].y + bv.y);
      r.z = leaky(acc[c4].z + bv.z); r.w = leaky(acc[c4].w + bv.w);
      *(float4*)(o + c4 * 4) = r;
    }
  }
}

extern "C" void kernel_launch(void* const* d_in, const int* in_sizes, int n_in,
                              void* d_out, int out_size, void* d_ws, size_t ws_size,
                              hipStream_t stream) {
  const float* qf   = (const float*)d_in[0];
  const float* qxyz = (const float*)d_in[1];
  const float* kvf  = (const float*)d_in[2];
  const float* kxyz = (const float*)d_in[3];
  const float* w1 = (const float*)d_in[4];
  const float* g1 = (const float*)d_in[5];
  const float* b1 = (const float*)d_in[6];
  const float* m1 = (const float*)d_in[7];
  const float* v1 = (const float*)d_in[8];
  const float* w2 = (const float*)d_in[9];
  const float* g2 = (const float*)d_in[10];
  const float* b2 = (const float*)d_in[11];
  const float* m2 = (const float*)d_in[12];
  const float* v2 = (const float*)d_in[13];
  char* ws = (char*)d_ws;
  double* pd = (double*)(ws + OFF_PD);

  size_t need8 = (size_t)OFF_PD + (size_t)Bz * NQ * 8 * KNN * sizeof(double);
  bool big = ws_size >= need8;

  k_prep<<<129, 256, 0, stream>>>(qxyz, kxyz, w1, g1, b1, m1, v1, w2, g2, b2, m2, v2, ws);
  if (big) {
    k_sel<512><<<dim3(NQ / 256, 8, Bz), 256, 0, stream>>>(ws, pd);
  } else {
    k_sel<1024><<<dim3(NQ / 256, 4, Bz), 256, 0, stream>>>(ws, pd);
  }
  k_feat<<<dim3(64, Bz, 2), 256, 0, stream>>>(kvf, qf, ws, ws);
  if (big) {
    k_tail<8><<<dim3(NQ / 32, Bz), 256, 0, stream>>>(pd, ws, (float*)d_out);
  } else {
    k_tail<4><<<dim3(NQ / 32, Bz), 256, 0, stream>>>(pd, ws, (float*)d_out);
  }
}